// Round 4
// baseline (965.700 us; speedup 1.0000x reference)
//
#include <hip/hip_runtime.h>
#include <math.h>

typedef float f2_t __attribute__((ext_vector_type(2)));

// ---------------- graph build ----------------

__global__ void k_init_deg(int* __restrict__ deg, int N) {
  int i = blockIdx.x * blockDim.x + threadIdx.x;
  if (i < N) deg[i] = 1;  // self-loop contributes 1 to every node's degree
}

__global__ void k_count(const int* __restrict__ dst, int* __restrict__ deg, int E) {
  int e = blockIdx.x * blockDim.x + threadIdx.x;
  if (e < E) atomicAdd(&deg[dst[e]], 1);
}

__global__ void k_dinv(const int* __restrict__ deg, float* __restrict__ dinv, int N) {
  int i = blockIdx.x * blockDim.x + threadIdx.x;
  if (i < N) dinv[i] = rsqrtf((float)deg[i]);
}

__global__ void k_scan_partial(const int* __restrict__ deg, int* __restrict__ rowptr,
                               int* __restrict__ bsums, int N) {
  __shared__ int s[1024];
  int tid = threadIdx.x;
  int idx = blockIdx.x * 1024 + tid;
  int v = (idx < N) ? (deg[idx] - 1) : 0;
  s[tid] = v;
  __syncthreads();
  for (int off = 1; off < 1024; off <<= 1) {
    int add = (tid >= off) ? s[tid - off] : 0;
    __syncthreads();
    s[tid] += add;
    __syncthreads();
  }
  if (idx <= N) rowptr[idx] = s[tid] - v;
  if (tid == 1023) bsums[blockIdx.x] = s[1023];
}

__global__ void k_scan_sums(int* __restrict__ bsums, int nb) {
  __shared__ int s[1024];
  int tid = threadIdx.x;
  int v = (tid < nb) ? bsums[tid] : 0;
  s[tid] = v;
  __syncthreads();
  for (int off = 1; off < 1024; off <<= 1) {
    int add = (tid >= off) ? s[tid - off] : 0;
    __syncthreads();
    s[tid] += add;
    __syncthreads();
  }
  if (tid < nb) bsums[tid] = s[tid] - v;
}

__global__ void k_add_offsets(int* __restrict__ rowptr, int* __restrict__ cursor,
                              const int* __restrict__ bsums, int N) {
  int idx = blockIdx.x * 1024 + threadIdx.x;
  if (idx <= N) {
    int v = rowptr[idx] + bsums[blockIdx.x];
    rowptr[idx] = v;
    if (idx < N) cursor[idx] = v;
  }
}

__global__ void k_scatter(const int* __restrict__ src, const int* __restrict__ dst,
                          const float* __restrict__ dinv, int* __restrict__ cursor,
                          int* __restrict__ col, float* __restrict__ wgt, int E) {
  int e = blockIdx.x * blockDim.x + threadIdx.x;
  if (e < E) {
    int s = src[e];
    int d = dst[e];
    int slot = atomicAdd(&cursor[d], 1);
    col[slot] = s;
    wgt[slot] = dinv[s] * dinv[d];
  }
}

// ---------------- diffusion ----------------

__global__ void k_init_acc(const float* __restrict__ x, float* __restrict__ acc,
                           const float* __restrict__ t_ptr, int total4) {
  int i = blockIdx.x * blockDim.x + threadIdx.x;
  if (i >= total4) return;
  float c0 = expf(-t_ptr[0]);
  float4 v = ((const float4*)x)[i];
  float4 o;
  o.x = c0 * v.x; o.y = c0 * v.y; o.z = c0 * v.z; o.w = c0 * v.w;
  ((float4*)acc)[i] = o;
}

// one wave per dst row; lane owns a float2 feature slice; 4 gather chains.
__global__ __launch_bounds__(256) void k_hop(
    const int* __restrict__ rowptr, const int* __restrict__ col,
    const float* __restrict__ wgt, const float* __restrict__ dinv,
    const float* __restrict__ hprev, float* __restrict__ hnext,
    float* __restrict__ acc, const float* __restrict__ t_ptr,
    int k, int N, int write_h) {
  int wave = threadIdx.x >> 6;
  int lane = threadIdx.x & 63;
  int r = blockIdx.x * 4 + wave;
  if (r >= N) return;
  float t = t_ptr[0];
  float coeff = expf(-t);
  for (int j = 1; j <= k; ++j) coeff *= t / (float)j;

  const float2* hp = (const float2*)hprev;
  float di = dinv[r];
  float2 hs = hp[(size_t)r * 64 + lane];
  float s0x = di * di * hs.x, s0y = di * di * hs.y;
  float s1x = 0.f, s1y = 0.f, s2x = 0.f, s2y = 0.f, s3x = 0.f, s3y = 0.f;
  int e = rowptr[r], end = rowptr[r + 1];
  // unroll-4: four independent gather/accumulate chains for MLP
  for (; e + 3 < end; e += 4) {
    int c0 = col[e], c1 = col[e + 1], c2 = col[e + 2], c3 = col[e + 3];
    float w0 = wgt[e], w1 = wgt[e + 1], w2 = wgt[e + 2], w3 = wgt[e + 3];
    float2 v0 = hp[(size_t)c0 * 64 + lane];
    float2 v1 = hp[(size_t)c1 * 64 + lane];
    float2 v2 = hp[(size_t)c2 * 64 + lane];
    float2 v3 = hp[(size_t)c3 * 64 + lane];
    s0x += w0 * v0.x; s0y += w0 * v0.y;
    s1x += w1 * v1.x; s1y += w1 * v1.y;
    s2x += w2 * v2.x; s2y += w2 * v2.y;
    s3x += w3 * v3.x; s3y += w3 * v3.y;
  }
  for (; e < end; ++e) {
    int c0 = col[e];
    float w0 = wgt[e];
    float2 v0 = hp[(size_t)c0 * 64 + lane];
    s0x += w0 * v0.x; s0y += w0 * v0.y;
  }
  float sx = (s0x + s1x) + (s2x + s3x);
  float sy = (s0y + s1y) + (s2y + s3y);
  f2_t sum; sum.x = sx; sum.y = sy;
  // nontemporal: h_next / acc have zero reuse inside this hop; keep L2 for gathers
  if (write_h) __builtin_nontemporal_store(sum, (f2_t*)hnext + (size_t)r * 64 + lane);
  f2_t a = __builtin_nontemporal_load((const f2_t*)acc + (size_t)r * 64 + lane);
  a.x += coeff * sum.x;
  a.y += coeff * sum.y;
  __builtin_nontemporal_store(a, (f2_t*)acc + (size_t)r * 64 + lane);
}

// ---------------- epilogue: out = acc @ W^T + b ----------------
// Register-tiled LDS GEMM. Block tile: 128 rows x 128 cols, K=128 in two
// 64-wide slabs. aS/wS: [row][kslab] with XOR swizzle swz(row)=((row>>1)&7)<<2
// applied to the k-quad index -> compute ds_read_b128: 16 (a) / 4 (w) distinct
// addresses over >=8 bank-groups = 2-way max (free, m136). Staging writes
// <=8-way on 8 instructions total (noise). 8x8 micro-tile/thread:
// 16 b128 reads per 256 FMA = 1 B/FMA -> ~16 us LDS/VALU bound.
__global__ __launch_bounds__(256) void k_matmul(
    const float* __restrict__ acc, const float* __restrict__ W,
    const float* __restrict__ bias, float* __restrict__ out, int N) {
  __shared__ float aS[128 * 64];
  __shared__ float wS[128 * 64];
  int tid = threadIdx.x;
  int rg = tid & 15;   // rows rg + 16*i
  int og = tid >> 4;   // cols og + 16*j
  int rbase = blockIdx.x * 128;

  float s[8][8];
#pragma unroll
  for (int i = 0; i < 8; ++i)
#pragma unroll
    for (int j = 0; j < 8; ++j) s[i][j] = 0.f;

  int sa[8], so[8], ab[8], ob[8];
#pragma unroll
  for (int i = 0; i < 8; ++i) {
    int r = rg + 16 * i;
    sa[i] = ((r >> 1) & 7) << 2;
    ab[i] = r * 64;
    int o = og + 16 * i;
    so[i] = ((o >> 1) & 7) << 2;
    ob[i] = o * 64;
  }

  for (int slab = 0; slab < 2; ++slab) {
    __syncthreads();
#pragma unroll
    for (int p = 0; p < 8; ++p) {
      int idx = p * 256 + tid;
      int r = idx >> 4;
      int kloc = (idx & 15) * 4;
      int swz = ((r >> 1) & 7) << 2;
      int gr = rbase + r; if (gr >= N) gr = N - 1;
      float4 va = *(const float4*)&acc[(size_t)gr * 128 + slab * 64 + kloc];
      *(float4*)&aS[r * 64 + (kloc ^ swz)] = va;
      float4 vw = *(const float4*)&W[(size_t)r * 128 + slab * 64 + kloc];
      *(float4*)&wS[r * 64 + (kloc ^ swz)] = vw;
    }
    __syncthreads();
#pragma unroll
    for (int kq = 0; kq < 16; ++kq) {
      int k0 = kq * 4;
      float4 a4[8], w4[8];
#pragma unroll
      for (int i = 0; i < 8; ++i) a4[i] = *(const float4*)&aS[ab[i] + (k0 ^ sa[i])];
#pragma unroll
      for (int j = 0; j < 8; ++j) w4[j] = *(const float4*)&wS[ob[j] + (k0 ^ so[j])];
#pragma unroll
      for (int i = 0; i < 8; ++i)
#pragma unroll
        for (int j = 0; j < 8; ++j)
          s[i][j] += a4[i].x * w4[j].x + a4[i].y * w4[j].y +
                     a4[i].z * w4[j].z + a4[i].w * w4[j].w;
    }
  }

  float bv[8];
#pragma unroll
  for (int j = 0; j < 8; ++j) bv[j] = bias[og + 16 * j];
#pragma unroll
  for (int i = 0; i < 8; ++i) {
    int r = rbase + rg + 16 * i;
    if (r < N) {
#pragma unroll
      for (int j = 0; j < 8; ++j)
        out[(size_t)r * 128 + og + 16 * j] = s[i][j] + bv[j];
    }
  }
}

// ---------------- launch ----------------

extern "C" void kernel_launch(void* const* d_in, const int* in_sizes, int n_in,
                              void* d_out, int out_size, void* d_ws, size_t ws_size,
                              hipStream_t stream) {
  const float* x = (const float*)d_in[0];
  const int* ei = (const int*)d_in[1];   // int32! (harness converts integer inputs)
  const float* t = (const float*)d_in[2];
  const float* W = (const float*)d_in[3];
  const float* b = (const float*)d_in[4];
  int N = in_sizes[0] / 128;
  int E = in_sizes[1] / 2;
  const int* srcp = ei;
  const int* dstp = ei + E;
  float* out = (float*)d_out;

  char* ws = (char*)d_ws;
  size_t off = 0;
  auto alloc = [&](size_t bytes) -> void* {
    void* p = ws + off;
    off += (bytes + 255) & ~(size_t)255;
    return p;
  };
  float* hA     = (float*)alloc((size_t)N * 128 * 4);
  float* accb   = (float*)alloc((size_t)N * 128 * 4);
  int*   deg    = (int*)alloc((size_t)N * 4);
  float* dinv   = (float*)alloc((size_t)N * 4);
  int*   rowptr = (int*)alloc((size_t)(N + 1) * 4);
  int*   cursor = (int*)alloc((size_t)N * 4);
  int*   bsums  = (int*)alloc(4096);
  int*   col    = (int*)alloc((size_t)E * 4);
  float* wgt    = (float*)alloc((size_t)E * 4);
  (void)ws_size;

  int nb_scan = (N + 1 + 1023) / 1024;

  k_init_deg<<<(N + 255) / 256, 256, 0, stream>>>(deg, N);
  k_count<<<(E + 255) / 256, 256, 0, stream>>>(dstp, deg, E);
  k_dinv<<<(N + 255) / 256, 256, 0, stream>>>(deg, dinv, N);
  k_scan_partial<<<nb_scan, 1024, 0, stream>>>(deg, rowptr, bsums, N);
  k_scan_sums<<<1, 1024, 0, stream>>>(bsums, nb_scan);
  k_add_offsets<<<nb_scan, 1024, 0, stream>>>(rowptr, cursor, bsums, N);
  k_scatter<<<(E + 255) / 256, 256, 0, stream>>>(srcp, dstp, dinv, cursor, col, wgt, E);
  k_init_acc<<<(N * 128 / 4 + 255) / 256, 256, 0, stream>>>(x, accb, t, N * 128 / 4);

  const float* hprev = x;
  float* bufs[2] = {hA, out};  // out serves as h ping-pong scratch until matmul
  for (int k = 1; k <= 10; ++k) {
    float* hnext = bufs[(k - 1) & 1];
    k_hop<<<(N + 3) / 4, 256, 0, stream>>>(rowptr, col, wgt, dinv, hprev, hnext,
                                           accb, t, k, N, (k < 10) ? 1 : 0);
    hprev = hnext;
  }
  k_matmul<<<(N + 127) / 128, 256, 0, stream>>>(accb, W, b, out, N);
}

// Round 5
// 755.246 us; speedup vs baseline: 1.2787x; 1.2787x over previous
//
#include <hip/hip_runtime.h>
#include <math.h>

typedef float f4 __attribute__((ext_vector_type(4)));

// ---------------- graph build ----------------

__global__ void k_init_deg(int* __restrict__ deg, int N) {
  int i = blockIdx.x * blockDim.x + threadIdx.x;
  if (i < N) deg[i] = 1;  // self-loop contributes 1 to every node's degree
}

__global__ void k_count(const int* __restrict__ dst, int* __restrict__ deg, int E) {
  int e = blockIdx.x * blockDim.x + threadIdx.x;
  if (e < E) atomicAdd(&deg[dst[e]], 1);
}

__global__ void k_dinv(const int* __restrict__ deg, float* __restrict__ dinv, int N) {
  int i = blockIdx.x * blockDim.x + threadIdx.x;
  if (i < N) dinv[i] = rsqrtf((float)deg[i]);
}

__global__ void k_scan_partial(const int* __restrict__ deg, int* __restrict__ rowptr,
                               int* __restrict__ bsums, int N) {
  __shared__ int s[1024];
  int tid = threadIdx.x;
  int idx = blockIdx.x * 1024 + tid;
  int v = (idx < N) ? (deg[idx] - 1) : 0;
  s[tid] = v;
  __syncthreads();
  for (int off = 1; off < 1024; off <<= 1) {
    int add = (tid >= off) ? s[tid - off] : 0;
    __syncthreads();
    s[tid] += add;
    __syncthreads();
  }
  if (idx <= N) rowptr[idx] = s[tid] - v;
  if (tid == 1023) bsums[blockIdx.x] = s[1023];
}

__global__ void k_scan_sums(int* __restrict__ bsums, int nb) {
  __shared__ int s[1024];
  int tid = threadIdx.x;
  int v = (tid < nb) ? bsums[tid] : 0;
  s[tid] = v;
  __syncthreads();
  for (int off = 1; off < 1024; off <<= 1) {
    int add = (tid >= off) ? s[tid - off] : 0;
    __syncthreads();
    s[tid] += add;
    __syncthreads();
  }
  if (tid < nb) bsums[tid] = s[tid] - v;
}

__global__ void k_add_offsets(int* __restrict__ rowptr, int* __restrict__ cursor,
                              const int* __restrict__ bsums, int N) {
  int idx = blockIdx.x * 1024 + threadIdx.x;
  if (idx <= N) {
    int v = rowptr[idx] + bsums[blockIdx.x];
    rowptr[idx] = v;
    if (idx < N) cursor[idx] = v;
  }
}

__global__ void k_scatter(const int* __restrict__ src, const int* __restrict__ dst,
                          const float* __restrict__ dinv, int* __restrict__ cursor,
                          int* __restrict__ col, float* __restrict__ wgt, int E) {
  int e = blockIdx.x * blockDim.x + threadIdx.x;
  if (e < E) {
    int s = src[e];
    int d = dst[e];
    int slot = atomicAdd(&cursor[d], 1);
    col[slot] = s;
    wgt[slot] = dinv[s] * dinv[d];
  }
}

// ---------------- diffusion ----------------

__global__ void k_init_acc(const float* __restrict__ x, float* __restrict__ acc,
                           const float* __restrict__ t_ptr, int total4) {
  int i = blockIdx.x * blockDim.x + threadIdx.x;
  if (i >= total4) return;
  float c0 = expf(-t_ptr[0]);
  f4 v = ((const f4*)x)[i];
  ((f4*)acc)[i] = c0 * v;
}

// one wave per dst row. Wave split 2x32: half = lane>>5 processes edge e+half,
// lane's float4 feature slice fl = lane&31 (32 lanes x 16B = full 128-f row).
// 2 chains x 2 edges = 4 edges in flight; __shfl_xor(32) combines halves.
__global__ __launch_bounds__(256) void k_hop(
    const int* __restrict__ rowptr, const int* __restrict__ col,
    const float* __restrict__ wgt, const float* __restrict__ dinv,
    const float* __restrict__ hprev, float* __restrict__ hnext,
    float* __restrict__ acc, const float* __restrict__ t_ptr,
    int k, int N, int write_h) {
  int wave = threadIdx.x >> 6;
  int lane = threadIdx.x & 63;
  int half = lane >> 5;
  int fl = lane & 31;
  int r = blockIdx.x * 4 + wave;
  if (r >= N) return;
  float t = t_ptr[0];
  float coeff = expf(-t);
  for (int j = 1; j <= k; ++j) coeff *= t / (float)j;

  const f4* h4 = (const f4*)hprev;
  f4 sA = {0.f, 0.f, 0.f, 0.f}, sB = {0.f, 0.f, 0.f, 0.f};
  int start = rowptr[r], end = rowptr[r + 1];
  int e0 = start + half;
  for (; e0 + 2 < end; e0 += 4) {
    int c0 = col[e0];       float w0 = wgt[e0];
    int c1 = col[e0 + 2];   float w1 = wgt[e0 + 2];
    f4 v0 = h4[(size_t)c0 * 32 + fl];
    f4 v1 = h4[(size_t)c1 * 32 + fl];
    sA += w0 * v0;
    sB += w1 * v1;
  }
  if (e0 < end) {
    int c0 = col[e0];
    float w0 = wgt[e0];
    f4 v0 = h4[(size_t)c0 * 32 + fl];
    sA += w0 * v0;
  }
  f4 s = sA + sB;
  // combine the two halves (each holds a disjoint edge subset, same features)
  s.x += __shfl_xor(s.x, 32);
  s.y += __shfl_xor(s.y, 32);
  s.z += __shfl_xor(s.z, 32);
  s.w += __shfl_xor(s.w, 32);
  if (half == 0) {
    float di = dinv[r];
    f4 hs = h4[(size_t)r * 32 + fl];
    s += (di * di) * hs;
    if (write_h) __builtin_nontemporal_store(s, (f4*)hnext + (size_t)r * 32 + fl);
    f4 a = __builtin_nontemporal_load((const f4*)acc + (size_t)r * 32 + fl);
    a += coeff * s;
    __builtin_nontemporal_store(a, (f4*)acc + (size_t)r * 32 + fl);
  }
}

// ---------------- epilogue: out = acc @ W^T + b ----------------
// Block tile 64 rows x 64 cols, full K=128 in LDS (aS+wS = 64 KB, 2 blk/CU).
// Thread tile 4x4 (rows rg+16i, cols 4*cg+j): 16 acc + 8 f4 operands ~ 80 VGPR
// (R4's 8x8 spilled at 256 VGPR -> 300 MB scratch traffic; this is the fix).
// LDS layout: row-major stride 128 floats, quad-swizzle q ^= (row&7):
//   a-reads: 8 bank-groups x 2 addrs (2-way, free m136); w-reads 2-way;
//   staging writes 4-way on 16 instrs total (noise).
__global__ __launch_bounds__(256) void k_matmul(
    const float* __restrict__ acc, const float* __restrict__ W,
    const float* __restrict__ bias, float* __restrict__ out, int N) {
  __shared__ float aS[64 * 128];
  __shared__ float wS[64 * 128];
  int tid = threadIdx.x;
  int rbase = blockIdx.x * 64;
  int cbase = blockIdx.y * 64;

  // staging: per wave 2 rows x 512B contiguous global reads (coalesced)
  {
    int kq = tid & 31, rr = tid >> 5;
#pragma unroll
    for (int p = 0; p < 8; ++p) {
      int r = p * 8 + rr;
      int gr = rbase + r; if (gr >= N) gr = N - 1;
      f4 va = *(const f4*)&acc[(size_t)gr * 128 + kq * 4];
      *(f4*)&aS[r * 128 + ((kq ^ (r & 7)) << 2)] = va;
      f4 vw = *(const f4*)&W[(size_t)(cbase + r) * 128 + kq * 4];
      *(f4*)&wS[r * 128 + ((kq ^ (r & 7)) << 2)] = vw;
    }
  }
  __syncthreads();

  int rg = tid & 15, cg = tid >> 4;
  int sa = rg & 7;
  float s[4][4];
#pragma unroll
  for (int i = 0; i < 4; ++i)
#pragma unroll
    for (int j = 0; j < 4; ++j) s[i][j] = 0.f;

#pragma unroll 4
  for (int kq = 0; kq < 32; ++kq) {
    f4 a4[4], w4[4];
#pragma unroll
    for (int i = 0; i < 4; ++i)
      a4[i] = *(const f4*)&aS[(rg + 16 * i) * 128 + ((kq ^ sa) << 2)];
#pragma unroll
    for (int j = 0; j < 4; ++j) {
      int c = 4 * cg + j;
      w4[j] = *(const f4*)&wS[c * 128 + ((kq ^ (c & 7)) << 2)];
    }
#pragma unroll
    for (int i = 0; i < 4; ++i)
#pragma unroll
      for (int j = 0; j < 4; ++j)
        s[i][j] += a4[i].x * w4[j].x + a4[i].y * w4[j].y +
                   a4[i].z * w4[j].z + a4[i].w * w4[j].w;
  }

  f4 bv = *(const f4*)&bias[cbase + 4 * cg];
#pragma unroll
  for (int i = 0; i < 4; ++i) {
    int r = rbase + rg + 16 * i;
    if (r < N) {
      f4 o;
      o.x = s[i][0] + bv.x; o.y = s[i][1] + bv.y;
      o.z = s[i][2] + bv.z; o.w = s[i][3] + bv.w;
      *(f4*)&out[(size_t)r * 128 + cbase + 4 * cg] = o;
    }
  }
}

// ---------------- launch ----------------

extern "C" void kernel_launch(void* const* d_in, const int* in_sizes, int n_in,
                              void* d_out, int out_size, void* d_ws, size_t ws_size,
                              hipStream_t stream) {
  const float* x = (const float*)d_in[0];
  const int* ei = (const int*)d_in[1];   // int32! (harness converts integer inputs)
  const float* t = (const float*)d_in[2];
  const float* W = (const float*)d_in[3];
  const float* b = (const float*)d_in[4];
  int N = in_sizes[0] / 128;
  int E = in_sizes[1] / 2;
  const int* srcp = ei;
  const int* dstp = ei + E;
  float* out = (float*)d_out;

  char* ws = (char*)d_ws;
  size_t off = 0;
  auto alloc = [&](size_t bytes) -> void* {
    void* p = ws + off;
    off += (bytes + 255) & ~(size_t)255;
    return p;
  };
  float* hA     = (float*)alloc((size_t)N * 128 * 4);
  float* accb   = (float*)alloc((size_t)N * 128 * 4);
  int*   deg    = (int*)alloc((size_t)N * 4);
  float* dinv   = (float*)alloc((size_t)N * 4);
  int*   rowptr = (int*)alloc((size_t)(N + 1) * 4);
  int*   cursor = (int*)alloc((size_t)N * 4);
  int*   bsums  = (int*)alloc(4096);
  int*   col    = (int*)alloc((size_t)E * 4);
  float* wgt    = (float*)alloc((size_t)E * 4);
  (void)ws_size;

  int nb_scan = (N + 1 + 1023) / 1024;

  k_init_deg<<<(N + 255) / 256, 256, 0, stream>>>(deg, N);
  k_count<<<(E + 255) / 256, 256, 0, stream>>>(dstp, deg, E);
  k_dinv<<<(N + 255) / 256, 256, 0, stream>>>(deg, dinv, N);
  k_scan_partial<<<nb_scan, 1024, 0, stream>>>(deg, rowptr, bsums, N);
  k_scan_sums<<<1, 1024, 0, stream>>>(bsums, nb_scan);
  k_add_offsets<<<nb_scan, 1024, 0, stream>>>(rowptr, cursor, bsums, N);
  k_scatter<<<(E + 255) / 256, 256, 0, stream>>>(srcp, dstp, dinv, cursor, col, wgt, E);
  k_init_acc<<<(N * 128 / 4 + 255) / 256, 256, 0, stream>>>(x, accb, t, N * 128 / 4);

  const float* hprev = x;
  float* bufs[2] = {hA, out};  // out serves as h ping-pong scratch until matmul
  for (int k = 1; k <= 10; ++k) {
    float* hnext = bufs[(k - 1) & 1];
    k_hop<<<(N + 3) / 4, 256, 0, stream>>>(rowptr, col, wgt, dinv, hprev, hnext,
                                           accb, t, k, N, (k < 10) ? 1 : 0);
    hprev = hnext;
  }
  dim3 mmg((N + 63) / 64, 2);
  k_matmul<<<mmg, 256, 0, stream>>>(accb, W, b, out, N);
}

// Round 6
// 708.062 us; speedup vs baseline: 1.3639x; 1.0666x over previous
//
#include <hip/hip_runtime.h>
#include <math.h>

typedef float f4 __attribute__((ext_vector_type(4)));

// ---------------- graph build ----------------

__global__ void k_init_deg(int* __restrict__ deg, int N) {
  int i = blockIdx.x * blockDim.x + threadIdx.x;
  if (i < N) deg[i] = 1;  // self-loop contributes 1 to every node's degree
}

__global__ void k_count(const int* __restrict__ dst, int* __restrict__ deg, int E) {
  int e = blockIdx.x * blockDim.x + threadIdx.x;
  if (e < E) atomicAdd(&deg[dst[e]], 1);
}

__global__ void k_dinv(const int* __restrict__ deg, float* __restrict__ dinv, int N) {
  int i = blockIdx.x * blockDim.x + threadIdx.x;
  if (i < N) dinv[i] = rsqrtf((float)deg[i]);
}

__global__ void k_scan_partial(const int* __restrict__ deg, int* __restrict__ rowptr,
                               int* __restrict__ bsums, int N) {
  __shared__ int s[1024];
  int tid = threadIdx.x;
  int idx = blockIdx.x * 1024 + tid;
  int v = (idx < N) ? (deg[idx] - 1) : 0;
  s[tid] = v;
  __syncthreads();
  for (int off = 1; off < 1024; off <<= 1) {
    int add = (tid >= off) ? s[tid - off] : 0;
    __syncthreads();
    s[tid] += add;
    __syncthreads();
  }
  if (idx <= N) rowptr[idx] = s[tid] - v;
  if (tid == 1023) bsums[blockIdx.x] = s[1023];
}

__global__ void k_scan_sums(int* __restrict__ bsums, int nb) {
  __shared__ int s[1024];
  int tid = threadIdx.x;
  int v = (tid < nb) ? bsums[tid] : 0;
  s[tid] = v;
  __syncthreads();
  for (int off = 1; off < 1024; off <<= 1) {
    int add = (tid >= off) ? s[tid - off] : 0;
    __syncthreads();
    s[tid] += add;
    __syncthreads();
  }
  if (tid < nb) bsums[tid] = s[tid] - v;
}

__global__ void k_add_offsets(int* __restrict__ rowptr, int* __restrict__ cursor,
                              const int* __restrict__ bsums, int N) {
  int idx = blockIdx.x * 1024 + threadIdx.x;
  if (idx <= N) {
    int v = rowptr[idx] + bsums[blockIdx.x];
    rowptr[idx] = v;
    if (idx < N) cursor[idx] = v;
  }
}

// packs (col, weight) into one 8-B record: one load per edge in the hop loop
__global__ void k_scatter(const int* __restrict__ src, const int* __restrict__ dst,
                          const float* __restrict__ dinv, int* __restrict__ cursor,
                          int2* __restrict__ colw, int E) {
  int e = blockIdx.x * blockDim.x + threadIdx.x;
  if (e < E) {
    int s = src[e];
    int d = dst[e];
    int slot = atomicAdd(&cursor[d], 1);
    colw[slot] = make_int2(s, __float_as_int(dinv[s] * dinv[d]));
  }
}

// ---------------- diffusion (Horner): y <- gs * (A_hat y_in) + c_j x ----------
// gs = c10 on the first hop (y_in conceptually = c10*x, gathered from x raw),
// gs = 1 otherwise. No running accumulator buffer at all.
// One wave per dst row; wave split 2x32: half processes every other edge,
// lane's float4 slice fl = lane&31; __shfl_xor(32) combines halves.
// Stores are NORMAL (not nontemporal): next hop's random gathers want y in L2/LLC.
__global__ __launch_bounds__(256) void k_hop(
    const int* __restrict__ rowptr, const int2* __restrict__ colw,
    const float* __restrict__ dinv, const float* __restrict__ xfeat,
    const float* __restrict__ yin, float* __restrict__ yout,
    const float* __restrict__ t_ptr, int j, int first, int N) {
  int wave = threadIdx.x >> 6;
  int lane = threadIdx.x & 63;
  int half = lane >> 5;
  int fl = lane & 31;
  int r = blockIdx.x * 4 + wave;
  if (r >= N) return;
  float t = t_ptr[0];
  float cj = expf(-t);
  for (int i = 1; i <= j; ++i) cj *= t / (float)i;
  float gs = first ? cj * t / (float)(j + 1) : 1.0f;  // c_{j+1} = c10 on first hop

  const f4* h4 = (const f4*)yin;
  const f4* x4 = (const f4*)xfeat;
  f4 sA = {0.f, 0.f, 0.f, 0.f}, sB = {0.f, 0.f, 0.f, 0.f};
  int start = rowptr[r], end = rowptr[r + 1];
  int e = start + half;
  for (; e + 2 < end; e += 4) {
    int2 c0 = colw[e];
    int2 c1 = colw[e + 2];
    f4 v0 = h4[(size_t)c0.x * 32 + fl];
    f4 v1 = h4[(size_t)c1.x * 32 + fl];
    sA += __int_as_float(c0.y) * v0;
    sB += __int_as_float(c1.y) * v1;
  }
  if (e < end) {
    int2 c0 = colw[e];
    sA += __int_as_float(c0.y) * h4[(size_t)c0.x * 32 + fl];
  }
  f4 s = sA + sB;
  s.x += __shfl_xor(s.x, 32);
  s.y += __shfl_xor(s.y, 32);
  s.z += __shfl_xor(s.z, 32);
  s.w += __shfl_xor(s.w, 32);
  if (half == 0) {
    float di = dinv[r];
    f4 xr = x4[(size_t)r * 32 + fl];
    f4 selfv = first ? xr : h4[(size_t)r * 32 + fl];  // self-loop source = y_in[r]
    s += (di * di) * selfv;
    s = gs * s + cj * xr;
    *((f4*)yout + (size_t)r * 32 + fl) = s;
  }
}

// ---------------- epilogue: out = y @ W^T + b ----------------
// Block tile 64x64, full K=128 in LDS (64 KB, 2 blk/CU). 4x4 thread tile
// (~80 VGPR, no spill — R4's 8x8 spilled at 256). Quad-swizzle q ^= (row&7):
// compute reads 2-way max (free, m136), staging writes 4-way on 16 instrs.
__global__ __launch_bounds__(256) void k_matmul(
    const float* __restrict__ acc, const float* __restrict__ W,
    const float* __restrict__ bias, float* __restrict__ out, int N) {
  __shared__ float aS[64 * 128];
  __shared__ float wS[64 * 128];
  int tid = threadIdx.x;
  int rbase = blockIdx.x * 64;
  int cbase = blockIdx.y * 64;

  {
    int kq = tid & 31, rr = tid >> 5;
#pragma unroll
    for (int p = 0; p < 8; ++p) {
      int r = p * 8 + rr;
      int gr = rbase + r; if (gr >= N) gr = N - 1;
      f4 va = *(const f4*)&acc[(size_t)gr * 128 + kq * 4];
      *(f4*)&aS[r * 128 + ((kq ^ (r & 7)) << 2)] = va;
      f4 vw = *(const f4*)&W[(size_t)(cbase + r) * 128 + kq * 4];
      *(f4*)&wS[r * 128 + ((kq ^ (r & 7)) << 2)] = vw;
    }
  }
  __syncthreads();

  int rg = tid & 15, cg = tid >> 4;
  int sa = rg & 7;
  float s[4][4];
#pragma unroll
  for (int i = 0; i < 4; ++i)
#pragma unroll
    for (int j = 0; j < 4; ++j) s[i][j] = 0.f;

#pragma unroll 4
  for (int kq = 0; kq < 32; ++kq) {
    f4 a4[4], w4[4];
#pragma unroll
    for (int i = 0; i < 4; ++i)
      a4[i] = *(const f4*)&aS[(rg + 16 * i) * 128 + ((kq ^ sa) << 2)];
#pragma unroll
    for (int j = 0; j < 4; ++j) {
      int c = 4 * cg + j;
      w4[j] = *(const f4*)&wS[c * 128 + ((kq ^ (c & 7)) << 2)];
    }
#pragma unroll
    for (int i = 0; i < 4; ++i)
#pragma unroll
      for (int j = 0; j < 4; ++j)
        s[i][j] += a4[i].x * w4[j].x + a4[i].y * w4[j].y +
                   a4[i].z * w4[j].z + a4[i].w * w4[j].w;
  }

  f4 bv = *(const f4*)&bias[cbase + 4 * cg];
#pragma unroll
  for (int i = 0; i < 4; ++i) {
    int r = rbase + rg + 16 * i;
    if (r < N) {
      f4 o;
      o.x = s[i][0] + bv.x; o.y = s[i][1] + bv.y;
      o.z = s[i][2] + bv.z; o.w = s[i][3] + bv.w;
      *(f4*)&out[(size_t)r * 128 + cbase + 4 * cg] = o;
    }
  }
}

// ---------------- launch ----------------

extern "C" void kernel_launch(void* const* d_in, const int* in_sizes, int n_in,
                              void* d_out, int out_size, void* d_ws, size_t ws_size,
                              hipStream_t stream) {
  const float* x = (const float*)d_in[0];
  const int* ei = (const int*)d_in[1];   // int32! (harness converts integer inputs)
  const float* t = (const float*)d_in[2];
  const float* W = (const float*)d_in[3];
  const float* b = (const float*)d_in[4];
  int N = in_sizes[0] / 128;
  int E = in_sizes[1] / 2;
  const int* srcp = ei;
  const int* dstp = ei + E;
  float* out = (float*)d_out;

  char* ws = (char*)d_ws;
  size_t off = 0;
  auto alloc = [&](size_t bytes) -> void* {
    void* p = ws + off;
    off += (bytes + 255) & ~(size_t)255;
    return p;
  };
  float* hA     = (float*)alloc((size_t)N * 128 * 4);
  int*   deg    = (int*)alloc((size_t)N * 4);
  float* dinv   = (float*)alloc((size_t)N * 4);
  int*   rowptr = (int*)alloc((size_t)(N + 1) * 4);
  int*   cursor = (int*)alloc((size_t)N * 4);
  int*   bsums  = (int*)alloc(4096);
  int2*  colw   = (int2*)alloc((size_t)E * 8);
  (void)ws_size;

  int nb_scan = (N + 1 + 1023) / 1024;

  k_init_deg<<<(N + 255) / 256, 256, 0, stream>>>(deg, N);
  k_count<<<(E + 255) / 256, 256, 0, stream>>>(dstp, deg, E);
  k_dinv<<<(N + 255) / 256, 256, 0, stream>>>(deg, dinv, N);
  k_scan_partial<<<nb_scan, 1024, 0, stream>>>(deg, rowptr, bsums, N);
  k_scan_sums<<<1, 1024, 0, stream>>>(bsums, nb_scan);
  k_add_offsets<<<nb_scan, 1024, 0, stream>>>(rowptr, cursor, bsums, N);
  k_scatter<<<(E + 255) / 256, 256, 0, stream>>>(srcp, dstp, dinv, cursor, colw, E);

  // Horner: y <- A_hat y + c_j x, j = 9..0; first hop gathers x with gs=c10.
  // Buffers: bufs[0]=out (scratch until matmul), bufs[1]=hA; 10th output -> hA
  // so k_matmul input (hA) never aliases its output (out).
  float* bufs[2] = {out, hA};
  const float* yin = x;
  for (int m = 0; m < 10; ++m) {
    float* yout = bufs[m & 1];
    k_hop<<<(N + 3) / 4, 256, 0, stream>>>(rowptr, colw, dinv, x, yin, yout,
                                           t, 9 - m, (m == 0) ? 1 : 0, N);
    yin = yout;
  }
  dim3 mmg((N + 63) / 64, 2);
  k_matmul<<<mmg, 256, 0, stream>>>(hA, W, b, out, N);
}

// Round 7
// 544.334 us; speedup vs baseline: 1.7741x; 1.3008x over previous
//
#include <hip/hip_runtime.h>
#include <math.h>

typedef float f4 __attribute__((ext_vector_type(4)));
typedef _Float16 h4 __attribute__((ext_vector_type(4)));

// ---------------- graph build ----------------
// deg buffer holds RAW dst-edge counts (memset 0 + k_count); true degree is
// cnt+1 (self-loop). dinv computed in k_scan_partial (fused, saves a dispatch).

__global__ void k_count(const int* __restrict__ dst, int* __restrict__ cnt, int E) {
  int e = blockIdx.x * blockDim.x + threadIdx.x;
  if (e < E) atomicAdd(&cnt[dst[e]], 1);
}

__global__ void k_scan_partial(const int* __restrict__ cnt, int* __restrict__ rowptr,
                               int* __restrict__ bsums, float* __restrict__ dinv, int N) {
  __shared__ int s[1024];
  int tid = threadIdx.x;
  int idx = blockIdx.x * 1024 + tid;
  int v = (idx < N) ? cnt[idx] : 0;
  if (idx < N) dinv[idx] = rsqrtf((float)(v + 1));  // fused dinv
  s[tid] = v;
  __syncthreads();
  for (int off = 1; off < 1024; off <<= 1) {
    int add = (tid >= off) ? s[tid - off] : 0;
    __syncthreads();
    s[tid] += add;
    __syncthreads();
  }
  if (idx <= N) rowptr[idx] = s[tid] - v;
  if (tid == 1023) bsums[blockIdx.x] = s[1023];
}

__global__ void k_scan_sums(int* __restrict__ bsums, int nb) {
  __shared__ int s[1024];
  int tid = threadIdx.x;
  int v = (tid < nb) ? bsums[tid] : 0;
  s[tid] = v;
  __syncthreads();
  for (int off = 1; off < 1024; off <<= 1) {
    int add = (tid >= off) ? s[tid - off] : 0;
    __syncthreads();
    s[tid] += add;
    __syncthreads();
  }
  if (tid < nb) bsums[tid] = s[tid] - v;
}

__global__ void k_add_offsets(int* __restrict__ rowptr, int* __restrict__ cursor,
                              const int* __restrict__ bsums, int N) {
  int idx = blockIdx.x * 1024 + threadIdx.x;
  if (idx <= N) {
    int v = rowptr[idx] + bsums[blockIdx.x];
    rowptr[idx] = v;
    if (idx < N) cursor[idx] = v;
  }
}

__global__ void k_scatter(const int* __restrict__ src, const int* __restrict__ dst,
                          const float* __restrict__ dinv, int* __restrict__ cursor,
                          int2* __restrict__ colw, int E) {
  int e = blockIdx.x * blockDim.x + threadIdx.x;
  if (e < E) {
    int s = src[e];
    int d = dst[e];
    int slot = atomicAdd(&cursor[d], 1);
    colw[slot] = make_int2(s, __float_as_int(dinv[s] * dinv[d]));
  }
}

// ---------------- diffusion (Horner): y <- gs*(A_hat y_in) + c_j x ----------
// IN16: gathered operand (and self term) is fp16; x / arithmetic stay fp32.
// OUT16: store y as fp16 (all hops except the last, which feeds the matmul).
// fp16 error budget: ~5e-4 absmax vs 1.92e-3 threshold (see journal R7).
// One wave per dst row; 2x32 split; 4 chains/half = 8 gathers in flight.
template <bool IN16, bool OUT16>
__global__ __launch_bounds__(256) void k_hop(
    const int* __restrict__ rowptr, const int2* __restrict__ colw,
    const float* __restrict__ dinv, const float* __restrict__ xfeat,
    const void* __restrict__ yin, void* __restrict__ yout,
    const float* __restrict__ t_ptr, int j, int N) {
  int wave = threadIdx.x >> 6;
  int lane = threadIdx.x & 63;
  int half = lane >> 5;
  int fl = lane & 31;
  int r = blockIdx.x * 4 + wave;
  if (r >= N) return;
  float t = t_ptr[0];
  float cj = expf(-t);
  for (int i = 1; i <= j; ++i) cj *= t / (float)i;
  float gs = IN16 ? 1.0f : cj * t / (float)(j + 1);  // first hop: gs = c_{j+1}

  const f4* x4 = (const f4*)xfeat;
  const f4* yf = (const f4*)yin;
  const h4* yh = (const h4*)yin;

  auto G = [&](int idx) -> f4 {
    if (IN16) return __builtin_convertvector(yh[(size_t)idx * 32 + fl], f4);
    else      return yf[(size_t)idx * 32 + fl];
  };

  f4 sA = {0,0,0,0}, sB = {0,0,0,0}, sC = {0,0,0,0}, sD = {0,0,0,0};
  int start = rowptr[r], end = rowptr[r + 1];
  int e = start + half;
  for (; e + 6 < end; e += 8) {
    int2 c0 = colw[e], c1 = colw[e + 2], c2 = colw[e + 4], c3 = colw[e + 6];
    sA += __int_as_float(c0.y) * G(c0.x);
    sB += __int_as_float(c1.y) * G(c1.x);
    sC += __int_as_float(c2.y) * G(c2.x);
    sD += __int_as_float(c3.y) * G(c3.x);
  }
  for (; e < end; e += 2) {
    int2 c0 = colw[e];
    sA += __int_as_float(c0.y) * G(c0.x);
  }
  f4 s = (sA + sB) + (sC + sD);
  s.x += __shfl_xor(s.x, 32);
  s.y += __shfl_xor(s.y, 32);
  s.z += __shfl_xor(s.z, 32);
  s.w += __shfl_xor(s.w, 32);
  if (half == 0) {
    float di = dinv[r];
    f4 xr = x4[(size_t)r * 32 + fl];
    f4 selfv = IN16 ? G(r) : xr;  // self-loop source = y_in[r] (x on first hop)
    s += (di * di) * selfv;
    s = gs * s + cj * xr;
    if (OUT16) ((h4*)yout)[(size_t)r * 32 + fl] = __builtin_convertvector(s, h4);
    else       ((f4*)yout)[(size_t)r * 32 + fl] = s;
  }
}

// ---------------- epilogue: out = y @ W^T + b ----------------
// Block tile 64x64, full K=128 in LDS (64 KB, 2 blk/CU). 4x4 thread tile
// (~80 VGPR, no spill). Quad-swizzle q ^= (row&7): compute reads 2-way max
// (free, m136), staging writes 4-way on 16 instrs.
__global__ __launch_bounds__(256) void k_matmul(
    const float* __restrict__ acc, const float* __restrict__ W,
    const float* __restrict__ bias, float* __restrict__ out, int N) {
  __shared__ float aS[64 * 128];
  __shared__ float wS[64 * 128];
  int tid = threadIdx.x;
  int rbase = blockIdx.x * 64;
  int cbase = blockIdx.y * 64;

  {
    int kq = tid & 31, rr = tid >> 5;
#pragma unroll
    for (int p = 0; p < 8; ++p) {
      int r = p * 8 + rr;
      int gr = rbase + r; if (gr >= N) gr = N - 1;
      f4 va = *(const f4*)&acc[(size_t)gr * 128 + kq * 4];
      *(f4*)&aS[r * 128 + ((kq ^ (r & 7)) << 2)] = va;
      f4 vw = *(const f4*)&W[(size_t)(cbase + r) * 128 + kq * 4];
      *(f4*)&wS[r * 128 + ((kq ^ (r & 7)) << 2)] = vw;
    }
  }
  __syncthreads();

  int rg = tid & 15, cg = tid >> 4;
  int sa = rg & 7;
  float s[4][4];
#pragma unroll
  for (int i = 0; i < 4; ++i)
#pragma unroll
    for (int j = 0; j < 4; ++j) s[i][j] = 0.f;

#pragma unroll 4
  for (int kq = 0; kq < 32; ++kq) {
    f4 a4[4], w4[4];
#pragma unroll
    for (int i = 0; i < 4; ++i)
      a4[i] = *(const f4*)&aS[(rg + 16 * i) * 128 + ((kq ^ sa) << 2)];
#pragma unroll
    for (int j = 0; j < 4; ++j) {
      int c = 4 * cg + j;
      w4[j] = *(const f4*)&wS[c * 128 + ((kq ^ (c & 7)) << 2)];
    }
#pragma unroll
    for (int i = 0; i < 4; ++i)
#pragma unroll
      for (int j = 0; j < 4; ++j)
        s[i][j] += a4[i].x * w4[j].x + a4[i].y * w4[j].y +
                   a4[i].z * w4[j].z + a4[i].w * w4[j].w;
  }

  f4 bv = *(const f4*)&bias[cbase + 4 * cg];
#pragma unroll
  for (int i = 0; i < 4; ++i) {
    int r = rbase + rg + 16 * i;
    if (r < N) {
      f4 o;
      o.x = s[i][0] + bv.x; o.y = s[i][1] + bv.y;
      o.z = s[i][2] + bv.z; o.w = s[i][3] + bv.w;
      *(f4*)&out[(size_t)r * 128 + cbase + 4 * cg] = o;
    }
  }
}

// ---------------- launch ----------------

extern "C" void kernel_launch(void* const* d_in, const int* in_sizes, int n_in,
                              void* d_out, int out_size, void* d_ws, size_t ws_size,
                              hipStream_t stream) {
  const float* x = (const float*)d_in[0];
  const int* ei = (const int*)d_in[1];   // int32! (harness converts integer inputs)
  const float* t = (const float*)d_in[2];
  const float* W = (const float*)d_in[3];
  const float* b = (const float*)d_in[4];
  int N = in_sizes[0] / 128;
  int E = in_sizes[1] / 2;
  const int* srcp = ei;
  const int* dstp = ei + E;
  float* out = (float*)d_out;

  char* ws = (char*)d_ws;
  size_t off = 0;
  auto alloc = [&](size_t bytes) -> void* {
    void* p = ws + off;
    off += (bytes + 255) & ~(size_t)255;
    return p;
  };
  float* hA     = (float*)alloc((size_t)N * 128 * 4);   // final y (fp32) for matmul
  void*  yh0    = alloc((size_t)N * 128 * 2);           // fp16 ping
  void*  yh1    = alloc((size_t)N * 128 * 2);           // fp16 pong
  int*   cnt    = (int*)alloc((size_t)N * 4);
  float* dinv   = (float*)alloc((size_t)N * 4);
  int*   rowptr = (int*)alloc((size_t)(N + 1) * 4);
  int*   cursor = (int*)alloc((size_t)N * 4);
  int*   bsums  = (int*)alloc(4096);
  int2*  colw   = (int2*)alloc((size_t)E * 8);
  (void)ws_size;  // ~57 MB total, known-OK from R3

  int nb_scan = (N + 1 + 1023) / 1024;

  hipMemsetAsync(cnt, 0, (size_t)N * 4, stream);
  k_count<<<(E + 255) / 256, 256, 0, stream>>>(dstp, cnt, E);
  k_scan_partial<<<nb_scan, 1024, 0, stream>>>(cnt, rowptr, bsums, dinv, N);
  k_scan_sums<<<1, 1024, 0, stream>>>(bsums, nb_scan);
  k_add_offsets<<<nb_scan, 1024, 0, stream>>>(rowptr, cursor, bsums, N);
  k_scatter<<<(E + 255) / 256, 256, 0, stream>>>(srcp, dstp, dinv, cursor, colw, E);

  // Horner: y <- A_hat y + c_j x, j = 9..0; first hop gathers x with gs=c10.
  int nblk = (N + 3) / 4;
  k_hop<false, true><<<nblk, 256, 0, stream>>>(rowptr, colw, dinv, x, x, yh0,
                                               t, 9, N);
  const void* yin = yh0;
  void* bufs[2] = {yh1, yh0};
  for (int m = 1; m <= 8; ++m) {
    void* yout = bufs[(m - 1) & 1];
    k_hop<true, true><<<nblk, 256, 0, stream>>>(rowptr, colw, dinv, x, yin, yout,
                                                t, 9 - m, N);
    yin = yout;
  }
  k_hop<true, false><<<nblk, 256, 0, stream>>>(rowptr, colw, dinv, x, yin, hA,
                                               t, 0, N);

  dim3 mmg((N + 63) / 64, 2);
  k_matmul<<<mmg, 256, 0, stream>>>(hA, W, b, out, N);
}

// Round 8
// 493.611 us; speedup vs baseline: 1.9564x; 1.1028x over previous
//
#include <hip/hip_runtime.h>
#include <math.h>

typedef float f4 __attribute__((ext_vector_type(4)));
typedef _Float16 h4 __attribute__((ext_vector_type(4)));

// ---------------- graph build ----------------
// cnt holds RAW dst-edge counts (memset 0 + k_count); true degree = cnt+1
// (self-loop). dinv fused into k_scan_partial.

__global__ void k_count(const int* __restrict__ dst, int* __restrict__ cnt, int E) {
  int e = blockIdx.x * blockDim.x + threadIdx.x;
  if (e < E) atomicAdd(&cnt[dst[e]], 1);
}

__global__ void k_scan_partial(const int* __restrict__ cnt, int* __restrict__ rowptr,
                               int* __restrict__ bsums, float* __restrict__ dinv, int N) {
  __shared__ int s[1024];
  int tid = threadIdx.x;
  int idx = blockIdx.x * 1024 + tid;
  int v = (idx < N) ? cnt[idx] : 0;
  if (idx < N) dinv[idx] = rsqrtf((float)(v + 1));
  s[tid] = v;
  __syncthreads();
  for (int off = 1; off < 1024; off <<= 1) {
    int add = (tid >= off) ? s[tid - off] : 0;
    __syncthreads();
    s[tid] += add;
    __syncthreads();
  }
  if (idx <= N) rowptr[idx] = s[tid] - v;
  if (tid == 1023) bsums[blockIdx.x] = s[1023];
}

__global__ void k_scan_sums(int* __restrict__ bsums, int nb) {
  __shared__ int s[1024];
  int tid = threadIdx.x;
  int v = (tid < nb) ? bsums[tid] : 0;
  s[tid] = v;
  __syncthreads();
  for (int off = 1; off < 1024; off <<= 1) {
    int add = (tid >= off) ? s[tid - off] : 0;
    __syncthreads();
    s[tid] += add;
    __syncthreads();
  }
  if (tid < nb) bsums[tid] = s[tid] - v;
}

__global__ void k_add_offsets(int* __restrict__ rowptr, int* __restrict__ cursor,
                              const int* __restrict__ bsums, int N) {
  int idx = blockIdx.x * 1024 + threadIdx.x;
  if (idx <= N) {
    int v = rowptr[idx] + bsums[blockIdx.x];
    rowptr[idx] = v;
    if (idx < N) cursor[idx] = v;
  }
}

__global__ void k_scatter(const int* __restrict__ src, const int* __restrict__ dst,
                          const float* __restrict__ dinv, int* __restrict__ cursor,
                          int2* __restrict__ colw, int E) {
  int e = blockIdx.x * blockDim.x + threadIdx.x;
  if (e < E) {
    int s = src[e];
    int d = dst[e];
    int slot = atomicAdd(&cursor[d], 1);
    colw[slot] = make_int2(s, __float_as_int(dinv[s] * dinv[d]));
  }
}

// one-time x -> fp16 copy (per-hop x-stream 25.6 -> 12.8 MB)
__global__ void k_tohalf(const float* __restrict__ x, _Float16* __restrict__ xh, int total4) {
  int i = blockIdx.x * blockDim.x + threadIdx.x;
  if (i < total4) ((h4*)xh)[i] = __builtin_convertvector(((const f4*)x)[i], h4);
}

// ---------------- diffusion (Horner): y <- gs*(A_hat y_in) + c_j xh ----------
// Half-per-row: wave = 2 rows, each 32-lane half owns row r = 2*waveRow+half.
// ~12.5 edges/row -> 3 full 4-chain iterations; no shuffles, both halves store.
// All operands fp16 (gathers, self, x); arithmetic fp32; output fp16.
// First hop: yin = xh, gs = c_{j+1} (folds the c10*x seed into the gather).
__global__ __launch_bounds__(256) void k_hop(
    const int* __restrict__ rowptr, const int2* __restrict__ colw,
    const float* __restrict__ dinv, const h4* __restrict__ xh,
    const h4* __restrict__ yin, h4* __restrict__ yout,
    const float* __restrict__ t_ptr, int j, int first, int N) {
  int wave = threadIdx.x >> 6;
  int lane = threadIdx.x & 63;
  int half = lane >> 5;
  int fl = lane & 31;
  int r = (blockIdx.x * 4 + wave) * 2 + half;
  if (r >= N) return;
  float t = t_ptr[0];
  float cj = expf(-t);
  for (int i = 1; i <= j; ++i) cj *= t / (float)i;
  float gs = first ? cj * t / (float)(j + 1) : 1.0f;

  auto G = [&](int idx) -> f4 {
    return __builtin_convertvector(yin[(size_t)idx * 32 + fl], f4);
  };

  f4 sA = {0,0,0,0}, sB = {0,0,0,0}, sC = {0,0,0,0}, sD = {0,0,0,0};
  int e = rowptr[r], end = rowptr[r + 1];
  for (; e + 3 < end; e += 4) {
    int2 c0 = colw[e], c1 = colw[e + 1], c2 = colw[e + 2], c3 = colw[e + 3];
    sA += __int_as_float(c0.y) * G(c0.x);
    sB += __int_as_float(c1.y) * G(c1.x);
    sC += __int_as_float(c2.y) * G(c2.x);
    sD += __int_as_float(c3.y) * G(c3.x);
  }
  for (; e < end; ++e) {
    int2 c0 = colw[e];
    sA += __int_as_float(c0.y) * G(c0.x);
  }
  f4 s = (sA + sB) + (sC + sD);
  float di = dinv[r];
  s += (di * di) * G(r);  // self-loop source = y_in[r] (xh on first hop)
  f4 xr = __builtin_convertvector(xh[(size_t)r * 32 + fl], f4);
  s = gs * s + cj * xr;
  yout[(size_t)r * 32 + fl] = __builtin_convertvector(s, h4);
}

// ---------------- epilogue: out = y16 @ W^T + b ----------------
// y input is fp16 (converted to fp32 during LDS staging; error ~2e-4, in budget).
// Block tile 64x64, K=128 in LDS (64 KB, 2 blk/CU). 4x4 thread tile (~80 VGPR,
// no spill). Quad-swizzle q ^= (row&7): compute reads 2-way max (free, m136).
__global__ __launch_bounds__(256) void k_matmul(
    const h4* __restrict__ y16, const float* __restrict__ W,
    const float* __restrict__ bias, float* __restrict__ out, int N) {
  __shared__ float aS[64 * 128];
  __shared__ float wS[64 * 128];
  int tid = threadIdx.x;
  int rbase = blockIdx.x * 64;
  int cbase = blockIdx.y * 64;

  {
    int kq = tid & 31, rr = tid >> 5;
#pragma unroll
    for (int p = 0; p < 8; ++p) {
      int r = p * 8 + rr;
      int gr = rbase + r; if (gr >= N) gr = N - 1;
      f4 va = __builtin_convertvector(y16[(size_t)gr * 32 + kq], f4);
      *(f4*)&aS[r * 128 + ((kq ^ (r & 7)) << 2)] = va;
      f4 vw = *(const f4*)&W[(size_t)(cbase + r) * 128 + kq * 4];
      *(f4*)&wS[r * 128 + ((kq ^ (r & 7)) << 2)] = vw;
    }
  }
  __syncthreads();

  int rg = tid & 15, cg = tid >> 4;
  int sa = rg & 7;
  float s[4][4];
#pragma unroll
  for (int i = 0; i < 4; ++i)
#pragma unroll
    for (int j = 0; j < 4; ++j) s[i][j] = 0.f;

#pragma unroll 4
  for (int kq = 0; kq < 32; ++kq) {
    f4 a4[4], w4[4];
#pragma unroll
    for (int i = 0; i < 4; ++i)
      a4[i] = *(const f4*)&aS[(rg + 16 * i) * 128 + ((kq ^ sa) << 2)];
#pragma unroll
    for (int j = 0; j < 4; ++j) {
      int c = 4 * cg + j;
      w4[j] = *(const f4*)&wS[c * 128 + ((kq ^ (c & 7)) << 2)];
    }
#pragma unroll
    for (int i = 0; i < 4; ++i)
#pragma unroll
      for (int j = 0; j < 4; ++j)
        s[i][j] += a4[i].x * w4[j].x + a4[i].y * w4[j].y +
                   a4[i].z * w4[j].z + a4[i].w * w4[j].w;
  }

  f4 bv = *(const f4*)&bias[cbase + 4 * cg];
#pragma unroll
  for (int i = 0; i < 4; ++i) {
    int r = rbase + rg + 16 * i;
    if (r < N) {
      f4 o;
      o.x = s[i][0] + bv.x; o.y = s[i][1] + bv.y;
      o.z = s[i][2] + bv.z; o.w = s[i][3] + bv.w;
      *(f4*)&out[(size_t)r * 128 + cbase + 4 * cg] = o;
    }
  }
}

// ---------------- launch ----------------

extern "C" void kernel_launch(void* const* d_in, const int* in_sizes, int n_in,
                              void* d_out, int out_size, void* d_ws, size_t ws_size,
                              hipStream_t stream) {
  const float* x = (const float*)d_in[0];
  const int* ei = (const int*)d_in[1];   // int32! (harness converts integer inputs)
  const float* t = (const float*)d_in[2];
  const float* W = (const float*)d_in[3];
  const float* b = (const float*)d_in[4];
  int N = in_sizes[0] / 128;
  int E = in_sizes[1] / 2;
  const int* srcp = ei;
  const int* dstp = ei + E;
  float* out = (float*)d_out;

  char* ws = (char*)d_ws;
  size_t off = 0;
  auto alloc = [&](size_t bytes) -> void* {
    void* p = ws + off;
    off += (bytes + 255) & ~(size_t)255;
    return p;
  };
  h4*    yh0    = (h4*)alloc((size_t)N * 128 * 2);  // fp16 ping
  h4*    yh1    = (h4*)alloc((size_t)N * 128 * 2);  // fp16 pong
  h4*    xh     = (h4*)alloc((size_t)N * 128 * 2);  // fp16 x
  int*   cnt    = (int*)alloc((size_t)N * 4);
  float* dinv   = (float*)alloc((size_t)N * 4);
  int*   rowptr = (int*)alloc((size_t)(N + 1) * 4);
  int*   cursor = (int*)alloc((size_t)N * 4);
  int*   bsums  = (int*)alloc(4096);
  int2*  colw   = (int2*)alloc((size_t)E * 8);
  (void)ws_size;  // ~44 MB total

  int nb_scan = (N + 1 + 1023) / 1024;

  hipMemsetAsync(cnt, 0, (size_t)N * 4, stream);
  k_count<<<(E + 255) / 256, 256, 0, stream>>>(dstp, cnt, E);
  k_scan_partial<<<nb_scan, 1024, 0, stream>>>(cnt, rowptr, bsums, dinv, N);
  k_scan_sums<<<1, 1024, 0, stream>>>(bsums, nb_scan);
  k_add_offsets<<<nb_scan, 1024, 0, stream>>>(rowptr, cursor, bsums, N);
  k_scatter<<<(E + 255) / 256, 256, 0, stream>>>(srcp, dstp, dinv, cursor, colw, E);
  k_tohalf<<<(N * 32 + 255) / 256, 256, 0, stream>>>(x, (_Float16*)xh, N * 32);

  // Horner: y <- A_hat y + c_j x, j = 9..0; first hop gathers xh with gs=c10.
  int nblk = (N + 7) / 8;  // 8 rows per 256-thread block (2 per wave)
  const h4* yin = xh;
  h4* bufs[2] = {yh0, yh1};
  for (int m = 0; m < 10; ++m) {
    h4* yout = bufs[m & 1];
    k_hop<<<nblk, 256, 0, stream>>>(rowptr, colw, dinv, xh, yin, yout,
                                    t, 9 - m, (m == 0) ? 1 : 0, N);
    yin = yout;
  }

  dim3 mmg((N + 63) / 64, 2);
  k_matmul<<<mmg, 256, 0, stream>>>(yin, W, b, out, N);
}

// Round 9
// 457.987 us; speedup vs baseline: 2.1086x; 1.0778x over previous
//
#include <hip/hip_runtime.h>
#include <math.h>

typedef float f4 __attribute__((ext_vector_type(4)));
typedef float f8 __attribute__((ext_vector_type(8)));
typedef _Float16 h8 __attribute__((ext_vector_type(8)));

// ---------------- graph build ----------------

__global__ void k_count(const int* __restrict__ dst, int* __restrict__ cnt, int E) {
  int e = blockIdx.x * blockDim.x + threadIdx.x;
  if (e < E) atomicAdd(&cnt[dst[e]], 1);
}

__global__ void k_scan_partial(const int* __restrict__ cnt, int* __restrict__ rowptr,
                               int* __restrict__ bsums, float* __restrict__ dinv, int N) {
  __shared__ int s[1024];
  int tid = threadIdx.x;
  int idx = blockIdx.x * 1024 + tid;
  int v = (idx < N) ? cnt[idx] : 0;
  if (idx < N) dinv[idx] = rsqrtf((float)(v + 1));
  s[tid] = v;
  __syncthreads();
  for (int off = 1; off < 1024; off <<= 1) {
    int add = (tid >= off) ? s[tid - off] : 0;
    __syncthreads();
    s[tid] += add;
    __syncthreads();
  }
  if (idx <= N) rowptr[idx] = s[tid] - v;
  if (tid == 1023) bsums[blockIdx.x] = s[1023];
}

__global__ void k_scan_sums(int* __restrict__ bsums, int nb) {
  __shared__ int s[1024];
  int tid = threadIdx.x;
  int v = (tid < nb) ? bsums[tid] : 0;
  s[tid] = v;
  __syncthreads();
  for (int off = 1; off < 1024; off <<= 1) {
    int add = (tid >= off) ? s[tid - off] : 0;
    __syncthreads();
    s[tid] += add;
    __syncthreads();
  }
  if (tid < nb) bsums[tid] = s[tid] - v;
}

__global__ void k_add_offsets(int* __restrict__ rowptr, int* __restrict__ cursor,
                              const int* __restrict__ bsums, int N) {
  int idx = blockIdx.x * 1024 + threadIdx.x;
  if (idx <= N) {
    int v = rowptr[idx] + bsums[blockIdx.x];
    rowptr[idx] = v;
    if (idx < N) cursor[idx] = v;
  }
}

__global__ void k_scatter(const int* __restrict__ src, const int* __restrict__ dst,
                          const float* __restrict__ dinv, int* __restrict__ cursor,
                          int2* __restrict__ colw, int E) {
  int e = blockIdx.x * blockDim.x + threadIdx.x;
  if (e < E) {
    int s = src[e];
    int d = dst[e];
    int slot = atomicAdd(&cursor[d], 1);
    colw[slot] = make_int2(s, __float_as_int(dinv[s] * dinv[d]));
  }
}

__global__ void k_tohalf(const float* __restrict__ x, _Float16* __restrict__ xh, int total8) {
  int i = blockIdx.x * blockDim.x + threadIdx.x;
  if (i < total8) {
    f4 a = ((const f4*)x)[i * 2], b = ((const f4*)x)[i * 2 + 1];
    f8 v = {a.x, a.y, a.z, a.w, b.x, b.y, b.z, b.w};
    ((h8*)xh)[i] = __builtin_convertvector(v, h8);
  }
}

// ---------------- diffusion (Horner): y <- gs*(A_hat y_in) + c_j xh ----------
// Quarter-per-row: wave = 4 rows; 16 lanes x 16B (h8) cover the 256-B fp16 row.
// 4 chains/quarter = 16 gathers (4 KB) in flight per wave; dwordx4 payload.
// Arithmetic fp32 (cvt+fma); output fp16. First hop: yin = xh, gs = c_{j+1}.
__global__ __launch_bounds__(256) void k_hop(
    const int* __restrict__ rowptr, const int2* __restrict__ colw,
    const float* __restrict__ dinv, const h8* __restrict__ xh,
    const h8* __restrict__ yin, h8* __restrict__ yout,
    const float* __restrict__ t_ptr, int j, int first, int N) {
  int wave = threadIdx.x >> 6;
  int lane = threadIdx.x & 63;
  int quarter = lane >> 4;
  int fl = lane & 15;
  int r = (blockIdx.x * 4 + wave) * 4 + quarter;
  if (r >= N) return;
  float t = t_ptr[0];
  float cj = expf(-t);
  for (int i = 1; i <= j; ++i) cj *= t / (float)i;
  float gs = first ? cj * t / (float)(j + 1) : 1.0f;

  auto G = [&](int idx) -> f8 {
    return __builtin_convertvector(yin[(size_t)idx * 16 + fl], f8);
  };

  f8 sA = {0,0,0,0,0,0,0,0}, sB = sA, sC = sA, sD = sA;
  int e = rowptr[r], end = rowptr[r + 1];
  for (; e + 3 < end; e += 4) {
    int2 c0 = colw[e], c1 = colw[e + 1], c2 = colw[e + 2], c3 = colw[e + 3];
    sA += __int_as_float(c0.y) * G(c0.x);
    sB += __int_as_float(c1.y) * G(c1.x);
    sC += __int_as_float(c2.y) * G(c2.x);
    sD += __int_as_float(c3.y) * G(c3.x);
  }
  for (; e < end; ++e) {
    int2 c0 = colw[e];
    sA += __int_as_float(c0.y) * G(c0.x);
  }
  f8 s = (sA + sB) + (sC + sD);
  float di = dinv[r];
  s += (di * di) * G(r);  // self-loop source = y_in[r] (xh on first hop)
  f8 xr = __builtin_convertvector(xh[(size_t)r * 16 + fl], f8);
  s = gs * s + cj * xr;
  yout[(size_t)r * 16 + fl] = __builtin_convertvector(s, h8);
}

// ---------------- epilogue: out = y16 @ W^T + b (MFMA fp16, W = hi+lo) ------
// Per block (4 waves, 128 rows): stage W as fp16 hi/lo into LDS (2x32 KB).
// LDS layout in 16-B granules: slot(n, g) = n*16 + (g ^ (n&7)) -> B-frag
// ds_read_b128 lands 2-way max per bank-group. A-frags read straight from
// global y16 (A[m=lane&15][k=quad*8+j] = 16 contiguous bytes per lane).
// D = A*Whi + A*Wlo accumulated fp32 => W-quantization error ~2^-22 (exact).
__global__ __launch_bounds__(256) void k_matmul(
    const h8* __restrict__ y16, const float* __restrict__ W,
    const float* __restrict__ bias, float* __restrict__ out, int N) {
  __shared__ h8 whiS[128 * 16];
  __shared__ h8 wloS[128 * 16];
  int tid = threadIdx.x;
  int rblk = blockIdx.x * 128;

  // stage W: 128 rows x 16 granules; hi = fp16(w), lo = fp16(w - fp32(hi))
#pragma unroll
  for (int it = 0; it < 8; ++it) {
    int idx = it * 256 + tid;
    int n = idx >> 4, g = idx & 15;
    f4 a = *(const f4*)&W[(size_t)n * 128 + g * 8];
    f4 b = *(const f4*)&W[(size_t)n * 128 + g * 8 + 4];
    f8 w = {a.x, a.y, a.z, a.w, b.x, b.y, b.z, b.w};
    h8 hi = __builtin_convertvector(w, h8);
    f8 hir = __builtin_convertvector(hi, f8);
    h8 lo = __builtin_convertvector(w - hir, h8);
    int slot = n * 16 + (g ^ (n & 7));
    whiS[slot] = hi;
    wloS[slot] = lo;
  }
  __syncthreads();

  int wave = tid >> 6, lane = tid & 63;
  int q = lane >> 4, fl = lane & 15;
  int rbase = rblk + wave * 32;  // this wave: rows rbase..rbase+31 (2 tiles)

  f4 acc[2][8];
#pragma unroll
  for (int rt = 0; rt < 2; ++rt)
#pragma unroll
    for (int nt = 0; nt < 8; ++nt) acc[rt][nt] = (f4){0.f, 0.f, 0.f, 0.f};

#pragma unroll
  for (int s = 0; s < 4; ++s) {  // K slabs of 32
    h8 aA, aB;
    {
      int r0 = rbase + fl;       if (r0 >= N) r0 = N - 1;
      int r1 = rbase + 16 + fl;  if (r1 >= N) r1 = N - 1;
      aA = y16[(size_t)r0 * 16 + s * 4 + q];
      aB = y16[(size_t)r1 * 16 + s * 4 + q];
    }
#pragma unroll
    for (int nt = 0; nt < 8; ++nt) {
      int n = nt * 16 + fl;
      int slot = n * 16 + ((s * 4 + q) ^ (n & 7));
      h8 bh = whiS[slot];
      h8 bl = wloS[slot];
      acc[0][nt] = __builtin_amdgcn_mfma_f32_16x16x32_f16(aA, bh, acc[0][nt], 0, 0, 0);
      acc[0][nt] = __builtin_amdgcn_mfma_f32_16x16x32_f16(aA, bl, acc[0][nt], 0, 0, 0);
      acc[1][nt] = __builtin_amdgcn_mfma_f32_16x16x32_f16(aB, bh, acc[1][nt], 0, 0, 0);
      acc[1][nt] = __builtin_amdgcn_mfma_f32_16x16x32_f16(aB, bl, acc[1][nt], 0, 0, 0);
    }
  }

  // epilogue: C/D layout col = lane&15, row = q*4 + reg
#pragma unroll
  for (int rt = 0; rt < 2; ++rt) {
#pragma unroll
    for (int nt = 0; nt < 8; ++nt) {
      float bv = bias[nt * 16 + fl];
#pragma unroll
      for (int reg = 0; reg < 4; ++reg) {
        int r = rbase + rt * 16 + q * 4 + reg;
        if (r < N) out[(size_t)r * 128 + nt * 16 + fl] = acc[rt][nt][reg] + bv;
      }
    }
  }
}

// ---------------- launch ----------------

extern "C" void kernel_launch(void* const* d_in, const int* in_sizes, int n_in,
                              void* d_out, int out_size, void* d_ws, size_t ws_size,
                              hipStream_t stream) {
  const float* x = (const float*)d_in[0];
  const int* ei = (const int*)d_in[1];   // int32! (harness converts integer inputs)
  const float* t = (const float*)d_in[2];
  const float* W = (const float*)d_in[3];
  const float* b = (const float*)d_in[4];
  int N = in_sizes[0] / 128;
  int E = in_sizes[1] / 2;
  const int* srcp = ei;
  const int* dstp = ei + E;
  float* out = (float*)d_out;

  char* ws = (char*)d_ws;
  size_t off = 0;
  auto alloc = [&](size_t bytes) -> void* {
    void* p = ws + off;
    off += (bytes + 255) & ~(size_t)255;
    return p;
  };
  h8*    yh0    = (h8*)alloc((size_t)N * 128 * 2);  // fp16 ping
  h8*    yh1    = (h8*)alloc((size_t)N * 128 * 2);  // fp16 pong
  h8*    xh     = (h8*)alloc((size_t)N * 128 * 2);  // fp16 x
  int*   cnt    = (int*)alloc((size_t)N * 4);
  float* dinv   = (float*)alloc((size_t)N * 4);
  int*   rowptr = (int*)alloc((size_t)(N + 1) * 4);
  int*   cursor = (int*)alloc((size_t)N * 4);
  int*   bsums  = (int*)alloc(4096);
  int2*  colw   = (int2*)alloc((size_t)E * 8);
  (void)ws_size;  // ~44 MB total

  int nb_scan = (N + 1 + 1023) / 1024;

  hipMemsetAsync(cnt, 0, (size_t)N * 4, stream);
  k_count<<<(E + 255) / 256, 256, 0, stream>>>(dstp, cnt, E);
  k_scan_partial<<<nb_scan, 1024, 0, stream>>>(cnt, rowptr, bsums, dinv, N);
  k_scan_sums<<<1, 1024, 0, stream>>>(bsums, nb_scan);
  k_add_offsets<<<nb_scan, 1024, 0, stream>>>(rowptr, cursor, bsums, N);
  k_scatter<<<(E + 255) / 256, 256, 0, stream>>>(srcp, dstp, dinv, cursor, colw, E);
  k_tohalf<<<(N * 16 + 255) / 256, 256, 0, stream>>>(x, (_Float16*)xh, N * 16);

  // Horner: y <- A_hat y + c_j x, j = 9..0; first hop gathers xh with gs=c10.
  int nblk = (N + 15) / 16;  // 16 rows per 256-thread block (4 per wave)
  const h8* yin = xh;
  h8* bufs[2] = {yh0, yh1};
  for (int m = 0; m < 10; ++m) {
    h8* yout = bufs[m & 1];
    k_hop<<<nblk, 256, 0, stream>>>(rowptr, colw, dinv, xh, yin, yout,
                                    t, 9 - m, (m == 0) ? 1 : 0, N);
    yin = yout;
  }

  k_matmul<<<(N + 127) / 128, 256, 0, stream>>>(yin, W, b, out, N);
}

// Round 10
// 445.181 us; speedup vs baseline: 2.1692x; 1.0288x over previous
//
#include <hip/hip_runtime.h>
#include <math.h>

typedef float f4 __attribute__((ext_vector_type(4)));
typedef float f8 __attribute__((ext_vector_type(8)));
typedef _Float16 h8 __attribute__((ext_vector_type(8)));

// ---------------- graph build ----------------
// CSR padded per-row to a multiple of 4 edges; padding slots are (col=0, w=0)
// via pre-memset of colw. Loop then has no cleanup and int4 edge loads align.

__global__ void k_count(const int* __restrict__ dst, int* __restrict__ cnt, int E) {
  int e = blockIdx.x * blockDim.x + threadIdx.x;
  if (e < E) atomicAdd(&cnt[dst[e]], 1);
}

__global__ void k_scan_partial(const int* __restrict__ cnt, int* __restrict__ rowptr,
                               int* __restrict__ bsums, float* __restrict__ dinv, int N) {
  __shared__ int s[1024];
  int tid = threadIdx.x;
  int idx = blockIdx.x * 1024 + tid;
  int v = (idx < N) ? cnt[idx] : 0;
  if (idx < N) dinv[idx] = rsqrtf((float)(v + 1));
  int vp = (v + 3) & ~3;  // padded row capacity
  s[tid] = vp;
  __syncthreads();
  for (int off = 1; off < 1024; off <<= 1) {
    int add = (tid >= off) ? s[tid - off] : 0;
    __syncthreads();
    s[tid] += add;
    __syncthreads();
  }
  if (idx <= N) rowptr[idx] = s[tid] - vp;
  if (tid == 1023) bsums[blockIdx.x] = s[1023];
}

__global__ void k_scan_sums(int* __restrict__ bsums, int nb) {
  __shared__ int s[1024];
  int tid = threadIdx.x;
  int v = (tid < nb) ? bsums[tid] : 0;
  s[tid] = v;
  __syncthreads();
  for (int off = 1; off < 1024; off <<= 1) {
    int add = (tid >= off) ? s[tid - off] : 0;
    __syncthreads();
    s[tid] += add;
    __syncthreads();
  }
  if (tid < nb) bsums[tid] = s[tid] - v;
}

__global__ void k_add_offsets(int* __restrict__ rowptr, int* __restrict__ cursor,
                              const int* __restrict__ bsums, int N) {
  int idx = blockIdx.x * 1024 + threadIdx.x;
  if (idx <= N) {
    int v = rowptr[idx] + bsums[blockIdx.x];
    rowptr[idx] = v;
    if (idx < N) cursor[idx] = v;
  }
}

__global__ void k_scatter(const int* __restrict__ src, const int* __restrict__ dst,
                          const float* __restrict__ dinv, int* __restrict__ cursor,
                          int2* __restrict__ colw, int E) {
  int e = blockIdx.x * blockDim.x + threadIdx.x;
  if (e < E) {
    int s = src[e];
    int d = dst[e];
    int slot = atomicAdd(&cursor[d], 1);
    colw[slot] = make_int2(s, __float_as_int(dinv[s] * dinv[d]));
  }
}

__global__ void k_tohalf(const float* __restrict__ x, _Float16* __restrict__ xh, int total8) {
  int i = blockIdx.x * blockDim.x + threadIdx.x;
  if (i < total8) {
    f4 a = ((const f4*)x)[i * 2], b = ((const f4*)x)[i * 2 + 1];
    f8 v = {a.x, a.y, a.z, a.w, b.x, b.y, b.z, b.w};
    ((h8*)xh)[i] = __builtin_convertvector(v, h8);
  }
}

// ---------------- diffusion (Horner): y <- gs*(A_hat y_in) + c_j xh ----------
// 8 groups of 8 lanes per wave: group g -> row (g>>1), feature-half (g&1).
// Each group runs 4 chains over the FULL (padded) edge list of its row:
// 8 chains in flight per row, 32 gathers/wave, 128-B gather granule (1 line),
// no cross-group reduction (halves are feature-disjoint), no cleanup loop.
__global__ __launch_bounds__(256) void k_hop(
    const int* __restrict__ rowptr, const int2* __restrict__ colw,
    const float* __restrict__ dinv, const h8* __restrict__ xh,
    const h8* __restrict__ yin, h8* __restrict__ yout,
    const float* __restrict__ t_ptr, int j, int first, int N) {
  int wave = threadIdx.x >> 6;
  int lane = threadIdx.x & 63;
  int grp = lane >> 3;
  int r = (blockIdx.x * 4 + wave) * 4 + (grp >> 1);
  if (r >= N) return;
  int fl = (lane & 7) + (grp & 1) * 8;  // h8 slot 0..15 within the row
  float t = t_ptr[0];
  float cj = expf(-t);
  for (int i = 1; i <= j; ++i) cj *= t / (float)i;
  float gs = first ? cj * t / (float)(j + 1) : 1.0f;

  auto G = [&](int idx) -> f8 {
    return __builtin_convertvector(yin[(size_t)idx * 16 + fl], f8);
  };

  f8 sA = {0,0,0,0,0,0,0,0}, sB = sA, sC = sA, sD = sA;
  int e = rowptr[r], end = rowptr[r + 1];  // end-e is a multiple of 4
  for (; e < end; e += 4) {
    int4 p0 = *(const int4*)&colw[e];      // edges e, e+1
    int4 p1 = *(const int4*)&colw[e + 2];  // edges e+2, e+3
    sA += __int_as_float(p0.y) * G(p0.x);
    sB += __int_as_float(p0.w) * G(p0.z);
    sC += __int_as_float(p1.y) * G(p1.x);
    sD += __int_as_float(p1.w) * G(p1.z);
  }
  f8 s = (sA + sB) + (sC + sD);
  float di = dinv[r];
  s += (di * di) * G(r);  // self-loop source = y_in[r] (xh on first hop)
  f8 xr = __builtin_convertvector(xh[(size_t)r * 16 + fl], f8);
  s = gs * s + cj * xr;
  yout[(size_t)r * 16 + fl] = __builtin_convertvector(s, h8);
}

// ---------------- epilogue: out = y16 @ W^T + b (MFMA fp16, W = hi+lo) ------
// W staged as fp16 hi/lo in LDS (2x32 KB), XOR-granule swizzle; A-frags read
// straight from global y16. fp32 accumulate; W-quant error ~2^-22 (exact).
__global__ __launch_bounds__(256) void k_matmul(
    const h8* __restrict__ y16, const float* __restrict__ W,
    const float* __restrict__ bias, float* __restrict__ out, int N) {
  __shared__ h8 whiS[128 * 16];
  __shared__ h8 wloS[128 * 16];
  int tid = threadIdx.x;
  int rblk = blockIdx.x * 128;

#pragma unroll
  for (int it = 0; it < 8; ++it) {
    int idx = it * 256 + tid;
    int n = idx >> 4, g = idx & 15;
    f4 a = *(const f4*)&W[(size_t)n * 128 + g * 8];
    f4 b = *(const f4*)&W[(size_t)n * 128 + g * 8 + 4];
    f8 w = {a.x, a.y, a.z, a.w, b.x, b.y, b.z, b.w};
    h8 hi = __builtin_convertvector(w, h8);
    f8 hir = __builtin_convertvector(hi, f8);
    h8 lo = __builtin_convertvector(w - hir, h8);
    int slot = n * 16 + (g ^ (n & 7));
    whiS[slot] = hi;
    wloS[slot] = lo;
  }
  __syncthreads();

  int wave = tid >> 6, lane = tid & 63;
  int q = lane >> 4, fl = lane & 15;
  int rbase = rblk + wave * 32;

  f4 acc[2][8];
#pragma unroll
  for (int rt = 0; rt < 2; ++rt)
#pragma unroll
    for (int nt = 0; nt < 8; ++nt) acc[rt][nt] = (f4){0.f, 0.f, 0.f, 0.f};

#pragma unroll
  for (int s = 0; s < 4; ++s) {
    h8 aA, aB;
    {
      int r0 = rbase + fl;       if (r0 >= N) r0 = N - 1;
      int r1 = rbase + 16 + fl;  if (r1 >= N) r1 = N - 1;
      aA = y16[(size_t)r0 * 16 + s * 4 + q];
      aB = y16[(size_t)r1 * 16 + s * 4 + q];
    }
#pragma unroll
    for (int nt = 0; nt < 8; ++nt) {
      int n = nt * 16 + fl;
      int slot = n * 16 + ((s * 4 + q) ^ (n & 7));
      h8 bh = whiS[slot];
      h8 bl = wloS[slot];
      acc[0][nt] = __builtin_amdgcn_mfma_f32_16x16x32_f16(aA, bh, acc[0][nt], 0, 0, 0);
      acc[0][nt] = __builtin_amdgcn_mfma_f32_16x16x32_f16(aA, bl, acc[0][nt], 0, 0, 0);
      acc[1][nt] = __builtin_amdgcn_mfma_f32_16x16x32_f16(aB, bh, acc[1][nt], 0, 0, 0);
      acc[1][nt] = __builtin_amdgcn_mfma_f32_16x16x32_f16(aB, bl, acc[1][nt], 0, 0, 0);
    }
  }

#pragma unroll
  for (int rt = 0; rt < 2; ++rt) {
#pragma unroll
    for (int nt = 0; nt < 8; ++nt) {
      float bv = bias[nt * 16 + fl];
#pragma unroll
      for (int reg = 0; reg < 4; ++reg) {
        int r = rbase + rt * 16 + q * 4 + reg;
        if (r < N) out[(size_t)r * 128 + nt * 16 + fl] = acc[rt][nt][reg] + bv;
      }
    }
  }
}

// ---------------- launch ----------------

extern "C" void kernel_launch(void* const* d_in, const int* in_sizes, int n_in,
                              void* d_out, int out_size, void* d_ws, size_t ws_size,
                              hipStream_t stream) {
  const float* x = (const float*)d_in[0];
  const int* ei = (const int*)d_in[1];   // int32! (harness converts integer inputs)
  const float* t = (const float*)d_in[2];
  const float* W = (const float*)d_in[3];
  const float* b = (const float*)d_in[4];
  int N = in_sizes[0] / 128;
  int E = in_sizes[1] / 2;
  const int* srcp = ei;
  const int* dstp = ei + E;
  float* out = (float*)d_out;

  char* ws = (char*)d_ws;
  size_t off = 0;
  auto alloc = [&](size_t bytes) -> void* {
    void* p = ws + off;
    off += (bytes + 255) & ~(size_t)255;
    return p;
  };
  h8*    yh0    = (h8*)alloc((size_t)N * 128 * 2);  // fp16 ping
  h8*    yh1    = (h8*)alloc((size_t)N * 128 * 2);  // fp16 pong
  h8*    xh     = (h8*)alloc((size_t)N * 128 * 2);  // fp16 x
  int*   cnt    = (int*)alloc((size_t)N * 4);
  float* dinv   = (float*)alloc((size_t)N * 4);
  int*   rowptr = (int*)alloc((size_t)(N + 1) * 4);
  int*   cursor = (int*)alloc((size_t)N * 4);
  int*   bsums  = (int*)alloc(4096);
  size_t colw_bytes = ((size_t)E + 4 * (size_t)N) * 8;  // padded-CSR upper bound
  int2*  colw   = (int2*)alloc(colw_bytes);
  (void)ws_size;  // ~46 MB total

  int nb_scan = (N + 1 + 1023) / 1024;

  hipMemsetAsync(cnt, 0, (size_t)N * 4, stream);
  hipMemsetAsync(colw, 0, colw_bytes, stream);  // padding slots: col=0, w=0
  k_count<<<(E + 255) / 256, 256, 0, stream>>>(dstp, cnt, E);
  k_scan_partial<<<nb_scan, 1024, 0, stream>>>(cnt, rowptr, bsums, dinv, N);
  k_scan_sums<<<1, 1024, 0, stream>>>(bsums, nb_scan);
  k_add_offsets<<<nb_scan, 1024, 0, stream>>>(rowptr, cursor, bsums, N);
  k_scatter<<<(E + 255) / 256, 256, 0, stream>>>(srcp, dstp, dinv, cursor, colw, E);
  k_tohalf<<<(N * 16 + 255) / 256, 256, 0, stream>>>(x, (_Float16*)xh, N * 16);

  // Horner: y <- A_hat y + c_j x, j = 9..0; first hop gathers xh with gs=c10.
  int nblk = (N + 15) / 16;  // 16 rows per 256-thread block (4 per wave)
  const h8* yin = xh;
  h8* bufs[2] = {yh0, yh1};
  for (int m = 0; m < 10; ++m) {
    h8* yout = bufs[m & 1];
    k_hop<<<nblk, 256, 0, stream>>>(rowptr, colw, dinv, xh, yin, yout,
                                    t, 9 - m, (m == 0) ? 1 : 0, N);
    yin = yout;
  }

  k_matmul<<<(N + 127) / 128, 256, 0, stream>>>(yin, W, b, out, N);
}